// Round 1
// 146.074 us; speedup vs baseline: 1.0173x; 1.0173x over previous
//
#include <hip/hip_runtime.h>

// ISTFT via batched real-IFFT (radix-4, in-place LDS) + gather-OA.
//
// Identity: reference einsum with W_real/W_imag == win ⊙ IDFT_2048(hermitian
// extension); Im F[0], Im F[1024] multiply zero sin-columns (dropped).
// Per frame (n=2048, m=1024):
//   1) real-IFFT pack (k=0..1023), 1/m normalization folded in:
//      Z[k] = [ (X[k]+conj(X[m-k])) + i e^{+2πik/n}(X[k]-conj(X[m-k])) ]*0.5/m
//   2) 1024-pt complex inverse FFT: radix-4 DIT, base-4-digit-reversed input,
//      e^{+} twiddles, 5 stages, IN-PLACE single LDS buffer.
//   3) x[2p]=Re z[p], x[2p+1]=Im z[p]; S[f][o] = bf16(win[o]*x[o])
//
// R9 vs R8 (theory: both kernels ~2.5x above their BW/VALU floors; overhead is
// barriers + LDS round-trips + scalar loads):
//  - radix-4 DIT butterfly is in-place (writes the same 4 indices it reads) ->
//    ping-pong buffer deleted.
//  - stage-s butterflies communicate only within thread groups of 4^s: stages
//    0..3 are wave-local (waves own disjoint 256-elem LDS regions), so only 2
//    HW barriers remain (post-pack scatter, pre-stage-4); stages 0..3 use
//    __builtin_amdgcn_wave_barrier() (zero-cost; same-wave DS ops are in-order).
//  - stage 4 fused with the windowed bf16 store: thread tid holds z[tid+q*256]
//    in registers -> coalesced dword stores; deletes one LDS round-trip.
//  - stage 0 twiddles are identically 1 (j==0): sincos + 3 cmuls dropped.
//  - norm: interior wss is EXACTLY 1.5 (Hann, hop=n/4: cos terms cancel over 4
//    phases), valid for all m in [512, 510976). Interior blocks: 8 outputs per
//    thread, uint4 (8xbf16) loads from the 4 t-streams, float4 stores, no win
//    loads. Edge blocks (first/last 512 outputs) keep the generic path.

#define N_FFT    2048
#define HOP      512
#define T_FRAMES 1000
#define F_BINS   1025
#define OUT_LEN  511488

#define P(a) ((a) + ((a) >> 4))            // LDS pad (complex units)

__device__ __forceinline__ void cmul(float ar, float ai, float br, float bi,
                                     float& cr, float& ci) {
    cr = ar * br - ai * bi;
    ci = ar * bi + ai * br;
}

__device__ __forceinline__ unsigned short f2bf(float f) {
    union { float f; unsigned int u; } v; v.f = f;
    unsigned int u = v.u;
    u += 0x7fffu + ((u >> 16) & 1u);       // round-to-nearest-even
    return (unsigned short)(u >> 16);
}

__device__ __forceinline__ float bf2f(unsigned short h) {
    union { unsigned int u; float f; } v;
    v.u = ((unsigned int)h) << 16;
    return v.f;
}

__global__ __launch_bounds__(256) void istft_fft_kernel(const float* __restrict__ re,
                                                        const float* __restrict__ im,
                                                        const float* __restrict__ win,
                                                        unsigned short* __restrict__ S) {
    __shared__ float2 buf[1088];           // P(1023)=1086

    const int f   = blockIdx.x;            // frame id = b*1000 + t
    const int tid = threadIdx.x;
    const float* fr = re + (size_t)f * F_BINS;
    const float* fi = im + (size_t)f * F_BINS;

    // ---- pack to Z, store base-4 digit-reversed ----
    const float Sc = 0.5f / 1024.f;
    #pragma unroll
    for (int k0 = 0; k0 < 1024; k0 += 256) {
        int k = k0 + tid;
        float ar = fr[k];
        float ai = (k == 0) ? 0.f : fi[k];          // Im F[0] dropped
        int mk = 1024 - k;
        float br = fr[mk];
        float bi = (mk == 1024) ? 0.f : fi[mk];     // Im F[1024] dropped
        float dr = ar - br, di = ai + bi;           // X[k] - conj(X[m-k])
        float ang = 3.14159265358979f * (float)k / 1024.f;
        float sn, cs;
        __sincosf(ang, &sn, &cs);
        float Zr = (ar + br - (cs * di + sn * dr)) * Sc;
        float Zi = (ai - bi + (cs * dr - sn * di)) * Sc;
        unsigned r10 = __brev((unsigned)k) >> 22;                       // 10b rev
        int rk = (int)(((r10 & 0x155u) << 1) | ((r10 >> 1) & 0x155u)); // digit-rev
        buf[P(rk)] = make_float2(Zr, Zi);
    }
    __syncthreads();   // digit-reversal scatter is cross-wave

    // ---- stage 0 (hm=1): twiddles == 1, in-place ----
    {
        int base = tid << 2;
        int i0 = P(base), i1 = P(base + 1), i2 = P(base + 2), i3 = P(base + 3);
        float2 a = buf[i0], b = buf[i1], c = buf[i2], d = buf[i3];
        float t0r = a.x + c.x, t0i = a.y + c.y;
        float t1r = a.x - c.x, t1i = a.y - c.y;
        float t2r = b.x + d.x, t2i = b.y + d.y;
        float t3r = b.x - d.x, t3i = b.y - d.y;
        buf[i0] = make_float2(t0r + t2r, t0i + t2i);
        buf[i1] = make_float2(t1r - t3i, t1i + t3r);   // + i*t3
        buf[i2] = make_float2(t0r - t2r, t0i - t2i);
        buf[i3] = make_float2(t1r + t3i, t1i - t3r);   // - i*t3
    }

    // ---- stages 1..3: wave-local (group = 4^s <= 64 threads; waves own
    //      disjoint 256-elem LDS regions) -> compiler fence only, no s_barrier.
    #pragma unroll
    for (int s = 1; s < 4; ++s) {
        __builtin_amdgcn_wave_barrier();
        const int hm = 1 << (2 * s);
        const int j    = tid & (hm - 1);
        const int base = ((tid - j) << 2) + j;
        float ang = 1.57079632679f * (float)j / (float)hm;   // 2π j/(4hm)
        float s1, c1;
        __sincosf(ang, &s1, &c1);                  // w1 = e^{+i ang}
        float c2, s2, c3, s3;
        cmul(c1, s1, c1, s1, c2, s2);              // w2 = w1^2
        cmul(c2, s2, c1, s1, c3, s3);              // w3 = w1^3

        int i0 = P(base), i1 = P(base + hm), i2 = P(base + 2 * hm), i3 = P(base + 3 * hm);
        float2 a = buf[i0], b = buf[i1], c = buf[i2], d = buf[i3];
        float br_, bi_, cr_, ci_, dr_, di_;
        cmul(b.x, b.y, c1, s1, br_, bi_);
        cmul(c.x, c.y, c2, s2, cr_, ci_);
        cmul(d.x, d.y, c3, s3, dr_, di_);

        float t0r = a.x + cr_, t0i = a.y + ci_;
        float t1r = a.x - cr_, t1i = a.y - ci_;
        float t2r = br_ + dr_, t2i = bi_ + di_;
        float t3r = br_ - dr_, t3i = bi_ - di_;
        buf[i0] = make_float2(t0r + t2r, t0i + t2i);
        buf[i1] = make_float2(t1r - t3i, t1i + t3r);
        buf[i2] = make_float2(t0r - t2r, t0i - t2i);
        buf[i3] = make_float2(t1r + t3i, t1i - t3r);
    }
    __syncthreads();   // stage 4 spans all 1024 points: cross-wave

    // ---- stage 4 (hm=256) fused with window + bf16 store ----
    {
        unsigned int* dst = (unsigned int*)(S + (size_t)f * N_FFT);
        const float2* w2v = (const float2*)win;

        float ang = 1.57079632679f * (float)tid / 256.f;
        float s1, c1;
        __sincosf(ang, &s1, &c1);
        float c2, s2, c3, s3;
        cmul(c1, s1, c1, s1, c2, s2);
        cmul(c2, s2, c1, s1, c3, s3);

        int i0 = P(tid), i1 = P(tid + 256), i2 = P(tid + 512), i3 = P(tid + 768);
        float2 a = buf[i0], b = buf[i1], c = buf[i2], d = buf[i3];
        float br_, bi_, cr_, ci_, dr_, di_;
        cmul(b.x, b.y, c1, s1, br_, bi_);
        cmul(c.x, c.y, c2, s2, cr_, ci_);
        cmul(d.x, d.y, c3, s3, dr_, di_);

        float t0r = a.x + cr_, t0i = a.y + ci_;
        float t1r = a.x - cr_, t1i = a.y - ci_;
        float t2r = br_ + dr_, t2i = bi_ + di_;
        float t3r = br_ - dr_, t3i = bi_ - di_;

        float2 z0 = make_float2(t0r + t2r, t0i + t2i);
        float2 z1 = make_float2(t1r - t3i, t1i + t3r);
        float2 z2 = make_float2(t0r - t2r, t0i - t2i);
        float2 z3 = make_float2(t1r + t3i, t1i - t3r);

        float2 w0 = w2v[tid],       w1 = w2v[tid + 256];
        float2 w2 = w2v[tid + 512], w3 = w2v[tid + 768];
        dst[tid]       = (unsigned int)f2bf(z0.x * w0.x) | ((unsigned int)f2bf(z0.y * w0.y) << 16);
        dst[tid + 256] = (unsigned int)f2bf(z1.x * w1.x) | ((unsigned int)f2bf(z1.y * w1.y) << 16);
        dst[tid + 512] = (unsigned int)f2bf(z2.x * w2.x) | ((unsigned int)f2bf(z2.y * w2.y) << 16);
        dst[tid + 768] = (unsigned int)f2bf(z3.x * w3.x) | ((unsigned int)f2bf(z3.y * w3.y) << 16);
    }
}

// out[b, m] = (sum_t S[b*1000+t][n-512t]) / wss(n),  n = m + 1024
// Interior (m in [512, 510976)): exactly 4 contributions and wss == 1.5
// exactly (Hann, hop = n_fft/4: the cos and cos2 terms cancel over the 4
// phases). 8 outputs/thread, uint4 (8x bf16) loads, float4 stores.
// Edge blocks (blockIdx.x == 0 or 249) use the generic gather.
__global__ __launch_bounds__(256) void norm_kernel(const unsigned short* __restrict__ S,
                                                   const float* __restrict__ win,
                                                   float* __restrict__ out) {
    const int b  = blockIdx.y;
    const int m0 = (blockIdx.x * 256 + threadIdx.x) * 8;

    if (blockIdx.x >= 1 && blockIdx.x <= 248) {
        // ---- fast interior path ----
        const int n0  = m0 + N_FFT / 2;
        const int thi = n0 >> 9;          // no clamp needed in interior
        const int r   = n0 & 511;         // 8-aligned; no 512-boundary crossing

        float acc[8] = {0.f, 0.f, 0.f, 0.f, 0.f, 0.f, 0.f, 0.f};
        #pragma unroll
        for (int kk = 0; kk < 4; ++kk) {
            const int t = thi - kk;
            const int o = r + (kk << 9);
            const uint4 v = *reinterpret_cast<const uint4*>(
                S + ((size_t)(b * T_FRAMES + t)) * N_FFT + o);
            const unsigned int u[4] = {v.x, v.y, v.z, v.w};
            #pragma unroll
            for (int q = 0; q < 4; ++q) {
                union { unsigned int u32; float f; } lo, hi;
                lo.u32 = u[q] << 16;             // bf16 elem 2q
                hi.u32 = u[q] & 0xffff0000u;     // bf16 elem 2q+1
                acc[2 * q]     += lo.f;
                acc[2 * q + 1] += hi.f;
            }
        }
        const float inv = 1.f / 1.5f;
        float* o_ptr = out + (size_t)b * OUT_LEN + m0;
        float4 v0 = make_float4(acc[0] * inv, acc[1] * inv, acc[2] * inv, acc[3] * inv);
        float4 v1 = make_float4(acc[4] * inv, acc[5] * inv, acc[6] * inv, acc[7] * inv);
        reinterpret_cast<float4*>(o_ptr)[0] = v0;
        reinterpret_cast<float4*>(o_ptr)[1] = v1;
    } else {
        // ---- edge path (first/last blocks) ----
        for (int e = 0; e < 8; ++e) {
            int m = m0 + e;
            if (m >= OUT_LEN) continue;
            int n = m + N_FFT / 2;
            int thi = n >> 9; if (thi > T_FRAMES - 1) thi = T_FRAMES - 1;
            int tlo = (n - (N_FFT - HOP)) >> 9; if (tlo < 0) tlo = 0;

            float sum = 0.f, wss = 0.f;
            for (int t = tlo; t <= thi; ++t) {
                int o = n - (t << 9);
                sum += bf2f(S[((size_t)(b * T_FRAMES + t)) * N_FFT + o]);
                float w = win[o];
                wss += w * w;
            }
            out[(size_t)b * OUT_LEN + m] = (wss > 1.17549435e-38f) ? sum / wss : sum;
        }
    }
}

extern "C" void kernel_launch(void* const* d_in, const int* in_sizes, int n_in,
                              void* d_out, int out_size, void* d_ws, size_t ws_size,
                              hipStream_t stream) {
    const float* re  = (const float*)d_in[0];
    const float* im  = (const float*)d_in[1];
    // d_in[2], d_in[3] (W_real, W_imag) unused: the FFT computes their action.
    const float* win = (const float*)d_in[4];
    float* out = (float*)d_out;

    unsigned short* S = (unsigned short*)d_ws;   // 8000*2048*2 = 32,768,000 B

    istft_fft_kernel<<<8000, 256, 0, stream>>>(re, im, win, S);
    // 250 * 2048 = 512000 >= 511488; blocks 0 and 249 take the generic path.
    norm_kernel<<<dim3(250, 8), 256, 0, stream>>>(S, win, out);
}